// Round 15
// baseline (1965.150 us; speedup 1.0000x reference)
//
#include <hip/hip_runtime.h>

#define S_LEN 512
#define BATCH 64
#define EDIM  128
#define HDIM  256
#define GDIM  1024   // 4*H
#define TDIM  64
#define NROW  32768  // S*B
#define HSTR  264    // hb row stride in shorts

typedef __attribute__((ext_vector_type(8))) short short8;
typedef __attribute__((ext_vector_type(4))) short short4v;
typedef __attribute__((ext_vector_type(4))) unsigned short us4;
typedef __attribute__((ext_vector_type(4))) float f32x4;
typedef unsigned long long ull;

__device__ __forceinline__ unsigned short f2bf(float f) {
  unsigned u = __float_as_uint(f);
  u += 0x7FFFu + ((u >> 16) & 1u);   // RNE
  return (unsigned short)(u >> 16);
}
__device__ __forceinline__ float bf2f(unsigned short h) {
  return __uint_as_float(((unsigned)h) << 16);
}
__device__ __forceinline__ float sigm(float x) {
  float e = __expf(-x);
  return __builtin_amdgcn_rcpf(1.f + e);
}
__device__ __forceinline__ float tanh_(float x) {
  float e = __expf(2.f * x);
  return 1.f - 2.f * __builtin_amdgcn_rcpf(e + 1.f);
}

// ---------------- Kernel 0: pack W_hh (4-way col-split frag order) + flags -
// frag id = ((((dir*4 + ch)*4 + w)*8 + kk)*4 + gi);  gi == gate (0..3).
// lane l: 8 bf16 = W[gi*256 + ch*64 + w*16 + cl][kk*32 + q*8 .. +7]
__global__ __launch_bounds__(256) void k_pack(
    const float* __restrict__ Whf, const float* __restrict__ Whb,
    unsigned short* __restrict__ wpk, int* __restrict__ flags) {
  const int fid = blockIdx.x * 256 + threadIdx.x;   // 65536 lane-frags
  const int l = fid & 63;
  int rest = fid >> 6;
  const int gi = rest & 3;  rest >>= 2;
  const int kk = rest & 7;  rest >>= 3;
  const int w  = rest & 3;  rest >>= 2;
  const int ch = rest & 3;  rest >>= 2;
  const int dir = rest;     // 0..1
  const int q = l >> 4, cl = l & 15;
  const float* Wh = dir ? Whb : Whf;
  const int row = gi * 256 + ch * 64 + w * 16 + cl;
  const float* src = Wh + (size_t)row * HDIM + kk * 32 + q * 8;
  float4 v0 = *(const float4*)src;
  float4 v1 = *(const float4*)(src + 4);
  short8 t8;
  t8[0] = (short)f2bf(v0.x); t8[1] = (short)f2bf(v0.y);
  t8[2] = (short)f2bf(v0.z); t8[3] = (short)f2bf(v0.w);
  t8[4] = (short)f2bf(v1.x); t8[5] = (short)f2bf(v1.y);
  t8[6] = (short)f2bf(v1.z); t8[7] = (short)f2bf(v1.w);
  *(short8*)(wpk + (size_t)fid * 8) = t8;
  // zero the sync flags every launch (stream-ordered before k_lstm)
  if (blockIdx.x == 0)
    for (int i = threadIdx.x; i < 512; i += 256) flags[i] = 0;
}

// ---------------- Kernel 1: gather + input projection (both directions) ----
// xqT layout: [s][gatecol(1024)][batch(64)] bf16.
__global__ __launch_bounds__(512) void k_proj(
    const int* __restrict__ tok, const float* __restrict__ emb,
    const float* __restrict__ Wf, const float* __restrict__ bihf, const float* __restrict__ bhhf,
    const float* __restrict__ Wb, const float* __restrict__ bihb, const float* __restrict__ bhhb,
    unsigned short* __restrict__ xqf, unsigned short* __restrict__ xqb) {
  __shared__ short xt[256 * 136];
  const int tid = threadIdx.x;
  const int rowbase = blockIdx.x * 256;
  const int dir = blockIdx.y;
  const float* W  = dir ? Wb   : Wf;
  const float* bi = dir ? bihb : bihf;
  const float* bh = dir ? bhhb : bhhf;
  unsigned short* xq = dir ? xqb : xqf;

  for (int i = tid; i < 256 * 32; i += 512) {
    int row = i >> 5, c4 = (i & 31) << 2;
    int t = tok[rowbase + row];
    float4 v = *(const float4*)(emb + (size_t)t * EDIM + c4);
    short4v p;
    p.x = (short)f2bf(v.x); p.y = (short)f2bf(v.y);
    p.z = (short)f2bf(v.z); p.w = (short)f2bf(v.w);
    *(short4v*)&xt[row * 136 + c4] = p;
  }
  __syncthreads();

  const int w = tid >> 6, l = tid & 63, q = l >> 4, cl = l & 15;

  short8 a[2][4];
#pragma unroll
  for (int rt = 0; rt < 2; ++rt)
#pragma unroll
    for (int kk = 0; kk < 4; ++kk)
      a[rt][kk] = *(const short8*)&xt[((2 * w + rt) * 16 + cl) * 136 + kk * 32 + q * 8];

  for (int ct = 0; ct < 64; ++ct) {
    const int colg = ct * 16 + cl;
    short8 bw[4];
#pragma unroll
    for (int kk = 0; kk < 4; ++kk) {
      const float* wp = W + (size_t)colg * EDIM + kk * 32 + q * 8;
      float4 w0 = *(const float4*)wp;
      float4 w1 = *(const float4*)(wp + 4);
      short8 t8;
      t8[0] = (short)f2bf(w0.x); t8[1] = (short)f2bf(w0.y);
      t8[2] = (short)f2bf(w0.z); t8[3] = (short)f2bf(w0.w);
      t8[4] = (short)f2bf(w1.x); t8[5] = (short)f2bf(w1.y);
      t8[6] = (short)f2bf(w1.z); t8[7] = (short)f2bf(w1.w);
      bw[kk] = t8;
    }
    float bias = bi[colg] + bh[colg];
#pragma unroll
    for (int rt = 0; rt < 2; ++rt) {
      f32x4 acc = {bias, bias, bias, bias};
#pragma unroll
      for (int kk = 0; kk < 4; ++kk)
        acc = __builtin_amdgcn_mfma_f32_16x16x32_bf16(a[rt][kk], bw[kk], acc, 0, 0, 0);
      const int rowg = rowbase + (2 * w + rt) * 16 + q * 4;
      const int s = rowg >> 6, b0 = rowg & 63;
      us4 p;
      p[0] = f2bf(acc[0]); p[1] = f2bf(acc[1]);
      p[2] = f2bf(acc[2]); p[3] = f2bf(acc[3]);
      *(us4*)&xq[((size_t)s * GDIM + colg) * BATCH + b0] = p;
    }
  }
}

// ---------------- Kernel 2: LSTM scans, 4-way col split, sc1 sync ----------
// grid = 32: bx = bg*8 + ch*2 + dir (bg-partners share xq lines on one XCD).
// 256 thr = 4 waves = 1/SIMD. W = 128 regs/wave, AGPR-resident (R14-proven).
// Sync: relaxed agent-scope (sc1/LLC) atomics only — no L2 wb/inv fences.
// hx layout: [par2][blk32][col64][row16] us — one 8B atomic store per lane.
__global__ __launch_bounds__(256, 1) __attribute__((amdgpu_waves_per_eu(1, 1)))
void k_lstm(
    const unsigned short* __restrict__ wpk,
    const unsigned short* __restrict__ xqf, const unsigned short* __restrict__ xqb,
    unsigned short* __restrict__ hq, unsigned short* __restrict__ hx,
    int* __restrict__ flags) {
  __shared__ short hb0[16][HSTR];
  __shared__ short hb1[16][HSTR];
  const int tid = threadIdx.x;
  const int bx = blockIdx.x;
  const int dir = bx & 1, ch = (bx >> 1) & 3, bg = bx >> 3;
  const int bxb8 = bx & ~7;                     // partner group base (bg*8)
  const int w = tid >> 6, l = tid & 63, q = l >> 4, cl = l & 15;
  const int brow = bg * 16 + q * 4;
  const int hcol = ch * 64 + w * 16 + cl;       // this lane's h column (0..255)
  const char* xqB = (const char*)(dir ? xqb : xqf);
  const char* wlp = (const char*)wpk + (size_t)((dir * 4 + ch) * 4 + w) * 32768 + l * 16;
  char* hxB = (char*)hx;

  for (int i = tid; i < 16 * HSTR; i += 256) { ((short*)hb0)[i] = 0; ((short*)hb1)[i] = 0; }

  // W fully stationary: 8 kk x 4 gates = 32 frags = 128 regs, loaded once
  short8 wst[8][4];
#pragma unroll
  for (int kk = 0; kk < 8; ++kk)
#pragma unroll
    for (int gi = 0; gi < 4; ++gi)
      wst[kk][gi] = *(const short8*)(wlp + (kk * 4 + gi) * 1024);

  int xlane[4];
#pragma unroll
  for (int gi = 0; gi < 4; ++gi)
    xlane[gi] = ((gi * 256 + hcol) * BATCH + brow) * 2;
  const int hq_lbyte = (brow * 512 + dir * 256 + hcol) * 2;

  const int sd  = dir ? -(GDIM * BATCH * 2) : (GDIM * BATCH * 2);
  const int hsd = dir ? -(BATCH * 512 * 2)  : (BATCH * 512 * 2);
  const int s0 = dir ? (S_LEN - 1) : 0;
  int xoff    = s0 * (GDIM * BATCH * 2);
  int hq_soff = s0 * (BATCH * 512 * 2);

  // hx own-publish: [col = w*16+cl][rows q*4..q*4+3] -> col*32 + q*8, 8B aligned
  const int hx_own = bx * 2048 + (w * 16 + cl) * 32 + q * 8;
  // gather decode: c = tid>>2 (0..63), rg = tid&3 (rows rg*4..rg*4+3)
  const int gc = tid >> 2, grg = tid & 3;

  us4 xp[4];
#pragma unroll
  for (int gi = 0; gi < 4; ++gi)
    xp[gi] = *(const us4*)(xqB + xoff + xlane[gi]);
  xoff += sd;

  float cst[4] = {0.f, 0.f, 0.f, 0.f};
  __syncthreads();

#define STEP4(RB, WB, PAR, T) {                                              \
    f32x4 acc[4];                                                            \
    const f32x4 zz = {0.f, 0.f, 0.f, 0.f};                                   \
    acc[0] = zz; acc[1] = zz; acc[2] = zz; acc[3] = zz;                      \
    _Pragma("unroll") for (int kk = 0; kk < 8; ++kk) {                       \
      short8 av = *(const short8*)&RB[cl][kk * 32 + q * 8];                  \
      _Pragma("unroll") for (int gi = 0; gi < 4; ++gi)                       \
        acc[gi] = __builtin_amdgcn_mfma_f32_16x16x32_bf16(av, wst[kk][gi], acc[gi], 0, 0, 0); \
    }                                                                        \
    ull hpack = 0;                                                           \
    _Pragma("unroll") for (int r = 0; r < 4; ++r) {                          \
      float gi_ = sigm(acc[0][r] + bf2f(xp[0][r]));                          \
      float gf  = sigm(acc[1][r] + bf2f(xp[1][r]));                          \
      float gg  = tanh_(acc[2][r] + bf2f(xp[2][r]));                         \
      float go  = sigm(acc[3][r] + bf2f(xp[3][r]));                          \
      float cn = gf * cst[r] + gi_ * gg;                                     \
      cst[r] = cn;                                                           \
      unsigned short hbv = f2bf(go * tanh_(cn));                             \
      WB[q * 4 + r][hcol] = (short)hbv;                                      \
      hpack |= (ull)hbv << (16 * r);                                         \
    }                                                                        \
    __hip_atomic_store((ull*)(hxB + (PAR) * 65536 + hx_own), hpack,          \
                       __ATOMIC_RELAXED, __HIP_MEMORY_SCOPE_AGENT);          \
    asm volatile("s_waitcnt vmcnt(0)" ::: "memory");                         \
    __builtin_amdgcn_s_barrier();                                            \
    asm volatile("" ::: "memory");                                           \
    if (tid == 0)                                                            \
      __hip_atomic_store(&flags[bx * 16], (T) + 1, __ATOMIC_RELAXED,         \
                         __HIP_MEMORY_SCOPE_AGENT);                          \
    asm volatile("" ::: "memory");                                           \
    /* hq stores fly during the spin (waited by NEXT step's vmcnt(0)) */     \
    _Pragma("unroll") for (int r = 0; r < 4; ++r)                            \
      *(unsigned short*)((char*)hq + hq_soff + hq_lbyte + r * 1024) =        \
          (unsigned short)(hpack >> (16 * r));                               \
    hq_soff += hsd;                                                          \
    _Pragma("unroll") for (int p = 0; p < 3; ++p) {                          \
      const int pc = (p < ch) ? p : p + 1;                                   \
      const int pbx = bxb8 + pc * 2 + dir;                                   \
      while (__hip_atomic_load(&flags[pbx * 16], __ATOMIC_RELAXED,           \
                               __HIP_MEMORY_SCOPE_AGENT) < (T) + 1) {}       \
    }                                                                        \
    asm volatile("" ::: "memory");                                           \
    _Pragma("unroll") for (int p = 0; p < 3; ++p) {                          \
      const int pc = (p < ch) ? p : p + 1;                                   \
      const int pbx = bxb8 + pc * 2 + dir;                                   \
      ull v = __hip_atomic_load(                                             \
          (const ull*)(hxB + (PAR) * 65536 + pbx * 2048 + gc * 32 + grg * 8),\
          __ATOMIC_RELAXED, __HIP_MEMORY_SCOPE_AGENT);                       \
      _Pragma("unroll") for (int j = 0; j < 4; ++j)                          \
        WB[grg * 4 + j][pc * 64 + gc] = (short)(unsigned short)(v >> (16 * j)); \
    }                                                                        \
    _Pragma("unroll") for (int gi = 0; gi < 4; ++gi)                         \
      xp[gi] = *(const us4*)(xqB + xoff + xlane[gi]);                        \
    if ((T) < S_LEN - 2) xoff += sd;                                         \
    asm volatile("s_waitcnt lgkmcnt(0)\n\ts_barrier" ::: "memory");          \
  }

  for (int it = 0; it < S_LEN / 2; ++it) {
    const int t = 2 * it;
    STEP4(hb0, hb1, 0, t);
    STEP4(hb1, hb0, 1, t + 1);
  }
#undef STEP4
}

// ---------------- Kernel 3: output projection ------------------------------
__global__ __launch_bounds__(256) void k_out(
    const unsigned short* __restrict__ hq, const float* __restrict__ Wo,
    const float* __restrict__ bo, float* __restrict__ out) {
  __shared__ short wlds[64 * 520];
  const int tid = threadIdx.x;
  for (int i = tid; i < 64 * 128; i += 256) {
    int row = i >> 7, c4 = (i & 127) << 2;
    float4 v = *(const float4*)(Wo + (size_t)row * 512 + c4);
    short4v p;
    p.x = (short)f2bf(v.x); p.y = (short)f2bf(v.y);
    p.z = (short)f2bf(v.z); p.w = (short)f2bf(v.w);
    *(short4v*)&wlds[row * 520 + c4] = p;
  }
  __syncthreads();

  const int w = tid >> 6, l = tid & 63, q = l >> 4, cl = l & 15;
  const int rtb = blockIdx.x * 64 + w * 16;

  short8 a[16];
#pragma unroll
  for (int kk = 0; kk < 16; ++kk)
    a[kk] = *(const short8*)&hq[(size_t)(rtb + cl) * 512 + kk * 32 + q * 8];

#pragma unroll
  for (int ct = 0; ct < 4; ++ct) {
    float bias = bo[ct * 16 + cl];
    f32x4 acc = {bias, bias, bias, bias};
#pragma unroll
    for (int kk = 0; kk < 16; ++kk) {
      short8 b = *(const short8*)&wlds[(ct * 16 + cl) * 520 + kk * 32 + q * 8];
      acc = __builtin_amdgcn_mfma_f32_16x16x32_bf16(a[kk], b, acc, 0, 0, 0);
    }
#pragma unroll
    for (int r = 0; r < 4; ++r)
      out[(size_t)(rtb + q * 4 + r) * TDIM + ct * 16 + cl] = acc[r];
  }
}

extern "C" void kernel_launch(void* const* d_in, const int* in_sizes, int n_in,
                              void* d_out, int out_size, void* d_ws, size_t ws_size,
                              hipStream_t stream) {
  const int*   tok  = (const int*)d_in[0];
  const float* emb  = (const float*)d_in[1];
  const float* Wihf = (const float*)d_in[2];
  const float* Whhf = (const float*)d_in[3];
  const float* bihf = (const float*)d_in[4];
  const float* bhhf = (const float*)d_in[5];
  const float* Wihb = (const float*)d_in[6];
  const float* Whhb = (const float*)d_in[7];
  const float* bihb = (const float*)d_in[8];
  const float* bhhb = (const float*)d_in[9];
  const float* Wo   = (const float*)d_in[10];
  const float* bo   = (const float*)d_in[11];
  float* out = (float*)d_out;

  char* ws = (char*)d_ws;
  unsigned short* xqf = (unsigned short*)ws;                                  // 64 MiB
  unsigned short* xqb = (unsigned short*)(ws + (size_t)NROW * GDIM * 2);      // 64 MiB
  unsigned short* hq  = (unsigned short*)(ws + (size_t)NROW * GDIM * 4);      // 32 MiB
  // scratch parked inside d_out (k_out fully overwrites d_out afterwards):
  unsigned short* wpk   = (unsigned short*)d_out;                             // 1 MiB
  unsigned short* hx    = (unsigned short*)((char*)d_out + (2u << 20));       // 128 KiB
  int*            flags = (int*)((char*)d_out + (4u << 20));                  // 2 KiB

  k_pack<<<256, 256, 0, stream>>>(Whhf, Whhb, wpk, flags);
  k_proj<<<dim3(128, 2), 512, 0, stream>>>(tok, emb, Wihf, bihf, bhhf,
                                           Wihb, bihb, bhhb, xqf, xqb);
  k_lstm<<<32, 256, 0, stream>>>(wpk, xqf, xqb, hq, hx, flags);
  k_out<<<512, 256, 0, stream>>>(hq, Wo, bo, out);
}

// Round 17
// 1896.933 us; speedup vs baseline: 1.0360x; 1.0360x over previous
//
#include <hip/hip_runtime.h>

#define S_LEN 512
#define BATCH 64
#define EDIM  128
#define HDIM  256
#define GDIM  1024   // 4*H
#define TDIM  64
#define NROW  32768  // S*B
#define HSTR  264    // hb row stride in shorts

typedef __attribute__((ext_vector_type(8))) short short8;
typedef __attribute__((ext_vector_type(4))) short short4v;
typedef __attribute__((ext_vector_type(4))) unsigned short us4;
typedef __attribute__((ext_vector_type(4))) float f32x4;
typedef unsigned long long ull;

__device__ __forceinline__ unsigned short f2bf(float f) {
  unsigned u = __float_as_uint(f);
  u += 0x7FFFu + ((u >> 16) & 1u);   // RNE
  return (unsigned short)(u >> 16);
}
__device__ __forceinline__ float bf2f(unsigned short h) {
  return __uint_as_float(((unsigned)h) << 16);
}
__device__ __forceinline__ float sigm(float x) {
  float e = __expf(-x);
  return __builtin_amdgcn_rcpf(1.f + e);
}
__device__ __forceinline__ float tanh_(float x) {
  float e = __expf(2.f * x);
  return 1.f - 2.f * __builtin_amdgcn_rcpf(e + 1.f);
}

// ---------------- Kernel 0: pack W_hh (4-way col-split frag order) + flags -
__global__ __launch_bounds__(256) void k_pack(
    const float* __restrict__ Whf, const float* __restrict__ Whb,
    unsigned short* __restrict__ wpk, int* __restrict__ flags) {
  const int fid = blockIdx.x * 256 + threadIdx.x;   // 65536 lane-frags
  const int l = fid & 63;
  int rest = fid >> 6;
  const int gi = rest & 3;  rest >>= 2;
  const int kk = rest & 7;  rest >>= 3;
  const int w  = rest & 3;  rest >>= 2;
  const int ch = rest & 3;  rest >>= 2;
  const int dir = rest;     // 0..1
  const int q = l >> 4, cl = l & 15;
  const float* Wh = dir ? Whb : Whf;
  const int row = gi * 256 + ch * 64 + w * 16 + cl;
  const float* src = Wh + (size_t)row * HDIM + kk * 32 + q * 8;
  float4 v0 = *(const float4*)src;
  float4 v1 = *(const float4*)(src + 4);
  short8 t8;
  t8[0] = (short)f2bf(v0.x); t8[1] = (short)f2bf(v0.y);
  t8[2] = (short)f2bf(v0.z); t8[3] = (short)f2bf(v0.w);
  t8[4] = (short)f2bf(v1.x); t8[5] = (short)f2bf(v1.y);
  t8[6] = (short)f2bf(v1.z); t8[7] = (short)f2bf(v1.w);
  *(short8*)(wpk + (size_t)fid * 8) = t8;
  if (blockIdx.x == 0)
    for (int i = threadIdx.x; i < 512; i += 256) flags[i] = 0;
}

// ---------------- Kernel 1: gather + input projection (both directions) ----
__global__ __launch_bounds__(512) void k_proj(
    const int* __restrict__ tok, const float* __restrict__ emb,
    const float* __restrict__ Wf, const float* __restrict__ bihf, const float* __restrict__ bhhf,
    const float* __restrict__ Wb, const float* __restrict__ bihb, const float* __restrict__ bhhb,
    unsigned short* __restrict__ xqf, unsigned short* __restrict__ xqb) {
  __shared__ short xt[256 * 136];
  const int tid = threadIdx.x;
  const int rowbase = blockIdx.x * 256;
  const int dir = blockIdx.y;
  const float* W  = dir ? Wb   : Wf;
  const float* bi = dir ? bihb : bihf;
  const float* bh = dir ? bhhb : bhhf;
  unsigned short* xq = dir ? xqb : xqf;

  for (int i = tid; i < 256 * 32; i += 512) {
    int row = i >> 5, c4 = (i & 31) << 2;
    int t = tok[rowbase + row];
    float4 v = *(const float4*)(emb + (size_t)t * EDIM + c4);
    short4v p;
    p.x = (short)f2bf(v.x); p.y = (short)f2bf(v.y);
    p.z = (short)f2bf(v.z); p.w = (short)f2bf(v.w);
    *(short4v*)&xt[row * 136 + c4] = p;
  }
  __syncthreads();

  const int w = tid >> 6, l = tid & 63, q = l >> 4, cl = l & 15;

  short8 a[2][4];
#pragma unroll
  for (int rt = 0; rt < 2; ++rt)
#pragma unroll
    for (int kk = 0; kk < 4; ++kk)
      a[rt][kk] = *(const short8*)&xt[((2 * w + rt) * 16 + cl) * 136 + kk * 32 + q * 8];

  for (int ct = 0; ct < 64; ++ct) {
    const int colg = ct * 16 + cl;
    short8 bw[4];
#pragma unroll
    for (int kk = 0; kk < 4; ++kk) {
      const float* wp = W + (size_t)colg * EDIM + kk * 32 + q * 8;
      float4 w0 = *(const float4*)wp;
      float4 w1 = *(const float4*)(wp + 4);
      short8 t8;
      t8[0] = (short)f2bf(w0.x); t8[1] = (short)f2bf(w0.y);
      t8[2] = (short)f2bf(w0.z); t8[3] = (short)f2bf(w0.w);
      t8[4] = (short)f2bf(w1.x); t8[5] = (short)f2bf(w1.y);
      t8[6] = (short)f2bf(w1.z); t8[7] = (short)f2bf(w1.w);
      bw[kk] = t8;
    }
    float bias = bi[colg] + bh[colg];
#pragma unroll
    for (int rt = 0; rt < 2; ++rt) {
      f32x4 acc = {bias, bias, bias, bias};
#pragma unroll
      for (int kk = 0; kk < 4; ++kk)
        acc = __builtin_amdgcn_mfma_f32_16x16x32_bf16(a[rt][kk], bw[kk], acc, 0, 0, 0);
      const int rowg = rowbase + (2 * w + rt) * 16 + q * 4;
      const int s = rowg >> 6, b0 = rowg & 63;
      us4 p;
      p[0] = f2bf(acc[0]); p[1] = f2bf(acc[1]);
      p[2] = f2bf(acc[2]); p[3] = f2bf(acc[3]);
      *(us4*)&xq[((size_t)s * GDIM + colg) * BATCH + b0] = p;
    }
  }
}

// ---------------- Kernel 2: LSTM scans, 4-way col split --------------------
// grid = 32: bx = dir*16 + bg*4 + ch (R14 labeling). 256 thr = 4 waves =
// 1/SIMD. W = 128 regs/wave, AGPR-resident (R14-proven).
// Sync protocol (R14/R15/R16 2x2-validated): relaxed agent-scope flags are
// correct ONLY with sc1-coherent data. So: publish via ONE 8B relaxed-AGENT
// atomic store per lane (after an in-register 4x4 lane transpose so the 8B
// is row-contiguous in R14's [row16][col64] hx layout), gather via 8B
// relaxed-AGENT atomic loads + contiguous ds_write_b64. hq stores after flag.
__global__ __launch_bounds__(256, 1) __attribute__((amdgpu_waves_per_eu(1, 1)))
void k_lstm(
    const unsigned short* __restrict__ wpk,
    const unsigned short* __restrict__ xqf, const unsigned short* __restrict__ xqb,
    unsigned short* __restrict__ hq, unsigned short* __restrict__ hx,
    int* __restrict__ flags) {
  __shared__ short hb0[16][HSTR];
  __shared__ short hb1[16][HSTR];
  const int tid = threadIdx.x;
  const int bx = blockIdx.x;
  const int ch = bx & 3, bg = (bx >> 2) & 3, dir = bx >> 4;
  const int bxb = bx & ~3;
  const int w = tid >> 6, l = tid & 63, q = l >> 4, cl = l & 15;
  const int brow = bg * 16 + q * 4;
  const int hcol = ch * 64 + w * 16 + cl;       // this lane's h column (0..255)
  const char* xqB = (const char*)(dir ? xqb : xqf);
  const char* wlp = (const char*)wpk + (size_t)((dir * 4 + ch) * 4 + w) * 32768 + l * 16;
  char* hxB = (char*)hx;

  for (int i = tid; i < 16 * HSTR; i += 256) { ((short*)hb0)[i] = 0; ((short*)hb1)[i] = 0; }

  // W fully stationary: 8 kk x 4 gates = 32 frags = 128 regs, loaded once
  short8 wst[8][4];
#pragma unroll
  for (int kk = 0; kk < 8; ++kk)
#pragma unroll
    for (int gi = 0; gi < 4; ++gi)
      wst[kk][gi] = *(const short8*)(wlp + (kk * 4 + gi) * 1024);

  int xlane[4];
#pragma unroll
  for (int gi = 0; gi < 4; ++gi)
    xlane[gi] = ((gi * 256 + hcol) * BATCH + brow) * 2;
  const int hq_lbyte = (brow * 512 + dir * 256 + hcol) * 2;

  const int sd  = dir ? -(GDIM * BATCH * 2) : (GDIM * BATCH * 2);
  const int hsd = dir ? -(BATCH * 512 * 2)  : (BATCH * 512 * 2);
  const int s0 = dir ? (S_LEN - 1) : 0;
  int xoff    = s0 * (GDIM * BATCH * 2);
  int hq_soff = s0 * (BATCH * 512 * 2);

  // hx: [par2][blk32][row16][col64] us (R14 layout).
  // publish (post-transpose): lane holds row q*4+(cl&3), cols w*16+(cl>>2)*4..+3
  const int hx_pub  = bx * 2048 + (q * 4 + (cl & 3)) * 128
                      + (w * 16 + (cl >> 2) * 4) * 2;           // 8B aligned
  const int hx_prow = (tid >> 4) * 128 + (tid & 15) * 8;        // partner gather

  us4 xp[4];
#pragma unroll
  for (int gi = 0; gi < 4; ++gi)
    xp[gi] = *(const us4*)(xqB + xoff + xlane[gi]);
  xoff += sd;

  float cst[4] = {0.f, 0.f, 0.f, 0.f};
  __syncthreads();

#define STEP4(RB, WB, PAR, T) {                                              \
    f32x4 acc[4];                                                            \
    const f32x4 zz = {0.f, 0.f, 0.f, 0.f};                                   \
    acc[0] = zz; acc[1] = zz; acc[2] = zz; acc[3] = zz;                      \
    _Pragma("unroll") for (int kk = 0; kk < 8; ++kk) {                       \
      short8 av = *(const short8*)&RB[cl][kk * 32 + q * 8];                  \
      _Pragma("unroll") for (int gi = 0; gi < 4; ++gi)                       \
        acc[gi] = __builtin_amdgcn_mfma_f32_16x16x32_bf16(av, wst[kk][gi], acc[gi], 0, 0, 0); \
    }                                                                        \
    ull hpack = 0;                                                           \
    _Pragma("unroll") for (int r = 0; r < 4; ++r) {                          \
      float gi_ = sigm(acc[0][r] + bf2f(xp[0][r]));                          \
      float gf  = sigm(acc[1][r] + bf2f(xp[1][r]));                          \
      float gg  = tanh_(acc[2][r] + bf2f(xp[2][r]));                         \
      float go  = sigm(acc[3][r] + bf2f(xp[3][r]));                          \
      float cn = gf * cst[r] + gi_ * gg;                                     \
      cst[r] = cn;                                                           \
      unsigned short hbv = f2bf(go * tanh_(cn));                             \
      WB[q * 4 + r][hcol] = (short)hbv;                                      \
      hpack |= (ull)hbv << (16 * r);                                         \
    }                                                                        \
    /* 4x4 u16 lane-transpose within cl&3 groups (2 shfl_xor + merges) */    \
    {                                                                        \
      ull tsh = (ull)__shfl_xor((long long)hpack, 2);                        \
      unsigned lox = (unsigned)hpack, hix = (unsigned)(hpack >> 32);         \
      unsigned lot = (unsigned)tsh,   hit = (unsigned)(tsh >> 32);           \
      unsigned a0 = (cl & 2) ? hit : lox;                                    \
      unsigned a1 = (cl & 2) ? hix : lot;                                    \
      ull x1 = (ull)a0 | ((ull)a1 << 32);                                    \
      ull t1 = (ull)__shfl_xor((long long)x1, 1);                            \
      unsigned blx = (unsigned)x1, bhx = (unsigned)(x1 >> 32);               \
      unsigned blt = (unsigned)t1, bht = (unsigned)(t1 >> 32);               \
      unsigned c0 = (cl & 1) ? ((blt >> 16) | (blx & 0xFFFF0000u))           \
                             : ((blx & 0xFFFFu) | (blt << 16));              \
      unsigned c1 = (cl & 1) ? ((bht >> 16) | (bhx & 0xFFFF0000u))           \
                             : ((bhx & 0xFFFFu) | (bht << 16));              \
      ull tpack = (ull)c0 | ((ull)c1 << 32);                                 \
      __hip_atomic_store((ull*)(hxB + (PAR) * 65536 + hx_pub), tpack,        \
                         __ATOMIC_RELAXED, __HIP_MEMORY_SCOPE_AGENT);        \
    }                                                                        \
    asm volatile("s_waitcnt vmcnt(0)" ::: "memory");                         \
    __builtin_amdgcn_s_barrier();                                            \
    asm volatile("" ::: "memory");                                           \
    if (tid == 0)                                                            \
      __hip_atomic_store(&flags[bx * 16], (T) + 1, __ATOMIC_RELAXED,         \
                         __HIP_MEMORY_SCOPE_AGENT);                          \
    asm volatile("" ::: "memory");                                           \
    /* hq stores fly during the spin (drained by NEXT step's vmcnt(0)) */    \
    _Pragma("unroll") for (int r = 0; r < 4; ++r)                            \
      *(unsigned short*)((char*)hq + hq_soff + hq_lbyte + r * 1024) =        \
          (unsigned short)(hpack >> (16 * r));                               \
    hq_soff += hsd;                                                          \
    if (tid < 3) {                                                           \
      const int pc = (tid < ch) ? tid : tid + 1;                             \
      while (__hip_atomic_load(&flags[(bxb + pc) * 16], __ATOMIC_RELAXED,    \
                               __HIP_MEMORY_SCOPE_AGENT) < (T) + 1) {}       \
    }                                                                        \
    __builtin_amdgcn_s_barrier();                                            \
    asm volatile("" ::: "memory");                                           \
    _Pragma("unroll") for (int p = 0; p < 3; ++p) {                          \
      const int pc = (p < ch) ? p : p + 1;                                   \
      ull v = __hip_atomic_load(                                             \
          (const ull*)(hxB + (PAR) * 65536 + (bxb + pc) * 2048 + hx_prow),   \
          __ATOMIC_RELAXED, __HIP_MEMORY_SCOPE_AGENT);                       \
      *(ull*)&WB[tid >> 4][pc * 64 + (tid & 15) * 4] = v;                    \
    }                                                                        \
    _Pragma("unroll") for (int gi = 0; gi < 4; ++gi)                         \
      xp[gi] = *(const us4*)(xqB + xoff + xlane[gi]);                        \
    if ((T) < S_LEN - 2) xoff += sd;                                         \
    asm volatile("s_waitcnt lgkmcnt(0)\n\ts_barrier" ::: "memory");          \
  }

  for (int it = 0; it < S_LEN / 2; ++it) {
    const int t = 2 * it;
    STEP4(hb0, hb1, 0, t);
    STEP4(hb1, hb0, 1, t + 1);
  }
#undef STEP4
}

// ---------------- Kernel 3: output projection ------------------------------
__global__ __launch_bounds__(256) void k_out(
    const unsigned short* __restrict__ hq, const float* __restrict__ Wo,
    const float* __restrict__ bo, float* __restrict__ out) {
  __shared__ short wlds[64 * 520];
  const int tid = threadIdx.x;
  for (int i = tid; i < 64 * 128; i += 256) {
    int row = i >> 7, c4 = (i & 127) << 2;
    float4 v = *(const float4*)(Wo + (size_t)row * 512 + c4);
    short4v p;
    p.x = (short)f2bf(v.x); p.y = (short)f2bf(v.y);
    p.z = (short)f2bf(v.z); p.w = (short)f2bf(v.w);
    *(short4v*)&wlds[row * 520 + c4] = p;
  }
  __syncthreads();

  const int w = tid >> 6, l = tid & 63, q = l >> 4, cl = l & 15;
  const int rtb = blockIdx.x * 64 + w * 16;

  short8 a[16];
#pragma unroll
  for (int kk = 0; kk < 16; ++kk)
    a[kk] = *(const short8*)&hq[(size_t)(rtb + cl) * 512 + kk * 32 + q * 8];

#pragma unroll
  for (int ct = 0; ct < 4; ++ct) {
    float bias = bo[ct * 16 + cl];
    f32x4 acc = {bias, bias, bias, bias};
#pragma unroll
    for (int kk = 0; kk < 16; ++kk) {
      short8 b = *(const short8*)&wlds[(ct * 16 + cl) * 520 + kk * 32 + q * 8];
      acc = __builtin_amdgcn_mfma_f32_16x16x32_bf16(a[kk], b, acc, 0, 0, 0);
    }
#pragma unroll
    for (int r = 0; r < 4; ++r)
      out[(size_t)(rtb + q * 4 + r) * TDIM + ct * 16 + cl] = acc[r];
  }
}

extern "C" void kernel_launch(void* const* d_in, const int* in_sizes, int n_in,
                              void* d_out, int out_size, void* d_ws, size_t ws_size,
                              hipStream_t stream) {
  const int*   tok  = (const int*)d_in[0];
  const float* emb  = (const float*)d_in[1];
  const float* Wihf = (const float*)d_in[2];
  const float* Whhf = (const float*)d_in[3];
  const float* bihf = (const float*)d_in[4];
  const float* bhhf = (const float*)d_in[5];
  const float* Wihb = (const float*)d_in[6];
  const float* Whhb = (const float*)d_in[7];
  const float* bihb = (const float*)d_in[8];
  const float* bhhb = (const float*)d_in[9];
  const float* Wo   = (const float*)d_in[10];
  const float* bo   = (const float*)d_in[11];
  float* out = (float*)d_out;

  char* ws = (char*)d_ws;
  unsigned short* xqf = (unsigned short*)ws;                                  // 64 MiB
  unsigned short* xqb = (unsigned short*)(ws + (size_t)NROW * GDIM * 2);      // 64 MiB
  unsigned short* hq  = (unsigned short*)(ws + (size_t)NROW * GDIM * 4);      // 32 MiB
  // scratch parked inside d_out (k_out fully overwrites d_out afterwards):
  unsigned short* wpk   = (unsigned short*)d_out;                             // 1 MiB
  unsigned short* hx    = (unsigned short*)((char*)d_out + (2u << 20));       // 128 KiB
  int*            flags = (int*)((char*)d_out + (4u << 20));                  // 2 KiB

  k_pack<<<256, 256, 0, stream>>>(Whhf, Whhb, wpk, flags);
  k_proj<<<dim3(128, 2), 512, 0, stream>>>(tok, emb, Wihf, bihf, bhhf,
                                           Wihb, bihb, bhhb, xqf, xqb);
  k_lstm<<<32, 256, 0, stream>>>(wpk, xqf, xqb, hq, hx, flags);
  k_out<<<512, 256, 0, stream>>>(hq, Wo, bo, out);
}